// Round 1
// baseline (565.783 us; speedup 1.0000x reference)
//
#include <hip/hip_runtime.h>

// ---------------------------------------------------------------------------
// GCN 2-layer forward on MI355X.
//   h1 = X @ W1                  (bf16 MFMA GEMM, 50000x512x256)
//   h2 = relu(Ahat @ h1 + b1)    (CSR gather-accumulate, bf16 msgs)
//   t2 = h2 @ W2                 (bf16 MFMA GEMM, 50000x256x64)
//   out = Ahat @ t2 + b2         (CSR gather-accumulate, fp32 out)
// Ahat = D^-1/2 (A + I) D^-1/2 built on device each call (counting sort).
// ---------------------------------------------------------------------------

typedef __bf16 bf16x8 __attribute__((ext_vector_type(8)));
typedef __bf16 bf16x4 __attribute__((ext_vector_type(4)));
typedef float  f32x4  __attribute__((ext_vector_type(4)));

#define N_NODES 50000
#define N_PAD   50048   // 391 * 128
#define F_IN    512
#define F_HID   256
#define F_OUT   64

// ---------------------------------------------------------------------------
// x (f32) -> bf16, padded rows zeroed. 8 elems per thread.
__global__ __launch_bounds__(256) void convx_kernel(
    const float* __restrict__ x, __bf16* __restrict__ xb,
    int rows, int rowspad, int C)
{
    size_t i = ((size_t)blockIdx.x * blockDim.x + threadIdx.x) * 8;
    size_t total = (size_t)rowspad * C;
    if (i >= total) return;
    size_t row = i / C;
    bf16x8 o;
    if (row < (size_t)rows) {
        const float4* p = (const float4*)(x + i);
        float4 a = p[0], b = p[1];
        o[0] = (__bf16)a.x; o[1] = (__bf16)a.y; o[2] = (__bf16)a.z; o[3] = (__bf16)a.w;
        o[4] = (__bf16)b.x; o[5] = (__bf16)b.y; o[6] = (__bf16)b.z; o[7] = (__bf16)b.w;
    } else {
        #pragma unroll
        for (int j = 0; j < 8; ++j) o[j] = (__bf16)0.f;
    }
    *(bf16x8*)(xb + i) = o;
}

// W [K][N] f32 -> WT [N][K] bf16 (transpose so MFMA B-fragments are contiguous k)
__global__ __launch_bounds__(256) void convw_kernel(
    const float* __restrict__ W, __bf16* __restrict__ WT, int K, int N)
{
    int i = blockIdx.x * blockDim.x + threadIdx.x;
    if (i >= N * K) return;
    int n = i / K, k = i - n * K;
    WT[i] = (__bf16)W[(size_t)k * N + n];
}

// ---------------------------------------------------------------------------
// CSR build: histogram of col, exclusive scan (+self-loop), counting-sort fill
__global__ __launch_bounds__(256) void count_kernel(
    const int* __restrict__ col, int E, int Nn, int* __restrict__ cnt)
{
    int e = blockIdx.x * blockDim.x + threadIdx.x;
    if (e < E) {
        int c = col[e];
        if ((unsigned)c < (unsigned)Nn) atomicAdd(&cnt[c], 1);
    }
}

__global__ __launch_bounds__(1024) void scan_kernel(
    const int* __restrict__ cnt, int* __restrict__ offs,
    float* __restrict__ dinv, int N)
{
    __shared__ int part[1024];
    const int t = threadIdx.x;
    const int per = (N + 1023) >> 10;
    int begin = t * per;
    int end = begin + per; if (end > N) end = N;
    int s = 0;
    for (int i = begin; i < end; ++i) s += cnt[i] + 1;   // +1: self loop
    part[t] = s;
    __syncthreads();
    for (int off = 1; off < 1024; off <<= 1) {
        int v = 0;
        if (t >= off) v = part[t - off];
        __syncthreads();
        part[t] += v;
        __syncthreads();
    }
    int run = (t > 0) ? part[t - 1] : 0;
    for (int i = begin; i < end; ++i) {
        offs[i] = run;
        int c = cnt[i] + 1;
        run += c;
        dinv[i] = rsqrtf((float)c);
    }
    if (t == 1023) offs[N] = run;   // thread 1023's chunk is empty/last -> total
}

__global__ __launch_bounds__(256) void fill_kernel(
    const int* __restrict__ row, const int* __restrict__ col,
    int E, int Nn, const int* __restrict__ offs,
    int* __restrict__ fill, int* __restrict__ srcidx)
{
    int e = blockIdx.x * blockDim.x + threadIdx.x;
    if (e < E) {
        int c = col[e];
        int r = row[e];
        if ((unsigned)c < (unsigned)Nn && (unsigned)r < (unsigned)Nn) {
            int p = offs[c] + atomicAdd(&fill[c], 1);
            srcidx[p] = r;
        }
    } else {
        int i = e - E;
        if (i < Nn) {
            int p = offs[i] + atomicAdd(&fill[i], 1);
            srcidx[p] = i;   // self loop
        }
    }
}

// ---------------------------------------------------------------------------
// bf16 MFMA GEMM: C[Mpad][N] = A[Mpad][K] * BT[N][K]^T, 256 threads (4 waves),
// 16x16x32 MFMA, reg-staged LDS with +16B row pad (bank-conflict reduction).
template<int WGM, int WGN, int FM, int FN>
__global__ __launch_bounds__(256) void gemm_kernel(
    const __bf16* __restrict__ A, const __bf16* __restrict__ BT,
    __bf16* __restrict__ C, int K, int N)
{
    constexpr int BM = WGM * FM * 16;
    constexpr int BN = WGN * FN * 16;
    constexpr int BK = 32;
    constexpr int LDT = BK + 8;          // bf16 stride 48 = 96B (16B-aligned, depairs banks)
    __shared__ __bf16 As[BM * LDT];
    __shared__ __bf16 Bs[BN * LDT];

    const int tid  = threadIdx.x;
    const int lane = tid & 63;
    const int wid  = tid >> 6;
    const int wm = wid / WGN, wn = wid % WGN;
    const int bm = blockIdx.x * BM;
    const int bn = blockIdx.y * BN;
    const int lr = lane & 15, kg = lane >> 4;

    const int arow = tid >> 2;           // 0..63
    const int achk = (tid & 3) * 8;      // k-offset of this thread's 16B chunk

    f32x4 acc[FM][FN] = {};

    for (int k0 = 0; k0 < K; k0 += BK) {
        bf16x8 ra[BM / 64], rb[BN / 64];
        #pragma unroll
        for (int p = 0; p < BM / 64; ++p)
            ra[p] = *(const bf16x8*)(A + (size_t)(bm + p * 64 + arow) * K + k0 + achk);
        #pragma unroll
        for (int p = 0; p < BN / 64; ++p)
            rb[p] = *(const bf16x8*)(BT + (size_t)(bn + p * 64 + arow) * K + k0 + achk);
        __syncthreads();
        #pragma unroll
        for (int p = 0; p < BM / 64; ++p)
            *(bf16x8*)(As + (p * 64 + arow) * LDT + achk) = ra[p];
        #pragma unroll
        for (int p = 0; p < BN / 64; ++p)
            *(bf16x8*)(Bs + (p * 64 + arow) * LDT + achk) = rb[p];
        __syncthreads();

        bf16x8 af[FM], bf[FN];
        #pragma unroll
        for (int m = 0; m < FM; ++m)
            af[m] = *(const bf16x8*)(As + (wm * FM * 16 + m * 16 + lr) * LDT + kg * 8);
        #pragma unroll
        for (int n = 0; n < FN; ++n)
            bf[n] = *(const bf16x8*)(Bs + (wn * FN * 16 + n * 16 + lr) * LDT + kg * 8);
        #pragma unroll
        for (int m = 0; m < FM; ++m)
            #pragma unroll
            for (int n = 0; n < FN; ++n)
                acc[m][n] = __builtin_amdgcn_mfma_f32_16x16x32_bf16(
                    af[m], bf[n], acc[m][n], 0, 0, 0);
    }

    // C/D layout: col = lane&15, row = (lane>>4)*4 + j   [measured m89/m91]
    const int crow0 = bm + wm * FM * 16 + kg * 4;
    const int ccol0 = bn + wn * FN * 16 + lr;
    #pragma unroll
    for (int m = 0; m < FM; ++m)
        #pragma unroll
        for (int n = 0; n < FN; ++n)
            #pragma unroll
            for (int j = 0; j < 4; ++j)
                C[(size_t)(crow0 + m * 16 + j) * N + (ccol0 + n * 16)] =
                    (__bf16)acc[m][n][j];
}

// ---------------------------------------------------------------------------
// CSR aggregation: one wave per node. out[n][f] = dinv[n]*sum_e dinv[src]*H[src][f] (+bias)
template<int F, int FP, bool RELU, bool BF16OUT>
__global__ __launch_bounds__(256) void agg_kernel(
    const __bf16* __restrict__ H,
    const int* __restrict__ offs, const int* __restrict__ srcidx,
    const float* __restrict__ dinv, const float* __restrict__ bias,
    __bf16* __restrict__ outb, float* __restrict__ outf,
    int Nn, int Mpad)
{
    const int lane = threadIdx.x & 63;
    const int node = blockIdx.x * 4 + (threadIdx.x >> 6);
    if (node >= Mpad) return;
    if (node >= Nn) {                       // zero pad rows (GEMM2 reads them)
        if (BF16OUT) {
            #pragma unroll
            for (int j = 0; j < FP; ++j)
                outb[(size_t)node * F + lane * FP + j] = (__bf16)0.f;
        }
        return;
    }
    const int e0 = offs[node], e1 = offs[node + 1];
    const float dv = dinv[node];
    float acc[FP] = {};
    for (int e = e0; e < e1; ++e) {
        int s = srcidx[e];
        float w = dinv[s];
        const __bf16* hp = H + (size_t)s * F + lane * FP;
        if constexpr (FP == 4) {
            bf16x4 v = *(const bf16x4*)hp;
            #pragma unroll
            for (int j = 0; j < 4; ++j) acc[j] += w * (float)v[j];
        } else {
            acc[0] += w * (float)hp[0];
        }
    }
    if constexpr (BF16OUT) {
        bf16x4 ov;
        #pragma unroll
        for (int j = 0; j < FP; ++j) {
            float r = dv * acc[j] + bias[lane * FP + j];
            if (RELU) r = fmaxf(r, 0.f);
            if constexpr (FP == 4) ov[j] = (__bf16)r;
            else outb[(size_t)node * F + lane] = (__bf16)r;
        }
        if constexpr (FP == 4)
            *(bf16x4*)(outb + (size_t)node * F + lane * 4) = ov;
    } else {
        #pragma unroll
        for (int j = 0; j < FP; ++j) {
            float r = dv * acc[j] + bias[lane * FP + j];
            if (RELU) r = fmaxf(r, 0.f);
            outf[(size_t)node * F + lane * FP + j] = r;
        }
    }
}

// ---------------------------------------------------------------------------
extern "C" void kernel_launch(void* const* d_in, const int* in_sizes, int n_in,
                              void* d_out, int out_size, void* d_ws, size_t ws_size,
                              hipStream_t stream)
{
    const float* x   = (const float*)d_in[0];
    const int*   ei  = (const int*)d_in[1];
    const float* W1  = (const float*)d_in[2];
    const float* b1  = (const float*)d_in[3];
    const float* W2  = (const float*)d_in[4];
    const float* b2  = (const float*)d_in[5];
    const int E  = in_sizes[1] / 2;
    const int Nn = N_NODES;
    const int E2 = E + Nn;
    const int* rowp = ei;
    const int* colp = ei + E;

    // workspace carve-up (256B aligned)
    char* w = (char*)d_ws;
    auto alloc = [&](size_t bytes) {
        char* p = w; w += (bytes + 255) & ~(size_t)255; return p;
    };
    __bf16* xbf  = (__bf16*)alloc((size_t)N_PAD * F_IN  * 2);  // also reused as h2
    __bf16* h1   = (__bf16*)alloc((size_t)N_PAD * F_HID * 2);  // also reused as t2
    __bf16* w1t  = (__bf16*)alloc((size_t)F_HID * F_IN  * 2);
    __bf16* w2t  = (__bf16*)alloc((size_t)F_OUT * F_HID * 2);
    int*    cnt  = (int*)  alloc((size_t)Nn * 4);
    int*    fil  = (int*)  alloc((size_t)Nn * 4);
    int*    offs = (int*)  alloc((size_t)(Nn + 1) * 4);
    float*  dinv = (float*)alloc((size_t)Nn * 4);
    int*    srcx = (int*)  alloc((size_t)E2 * 4);
    __bf16* h2 = xbf;   // x dead after GEMM1
    __bf16* t2 = h1;    // h1 dead after agg1

    hipMemsetAsync(cnt, 0, (size_t)Nn * 4, stream);
    hipMemsetAsync(fil, 0, (size_t)Nn * 4, stream);

    // dtype conversions
    convx_kernel<<<(N_PAD * F_IN / 8 + 255) / 256, 256, 0, stream>>>(
        x, xbf, Nn, N_PAD, F_IN);
    convw_kernel<<<(F_IN * F_HID + 255) / 256, 256, 0, stream>>>(W1, w1t, F_IN, F_HID);
    convw_kernel<<<(F_HID * F_OUT + 255) / 256, 256, 0, stream>>>(W2, w2t, F_HID, F_OUT);

    // CSR build
    count_kernel<<<(E + 255) / 256, 256, 0, stream>>>(colp, E, Nn, cnt);
    scan_kernel<<<1, 1024, 0, stream>>>(cnt, offs, dinv, Nn);
    fill_kernel<<<(E2 + 255) / 256, 256, 0, stream>>>(rowp, colp, E, Nn, offs, fil, srcx);

    // layer 1
    gemm_kernel<2, 2, 4, 4><<<dim3(N_PAD / 128, F_HID / 128), 256, 0, stream>>>(
        xbf, w1t, h1, F_IN, F_HID);
    agg_kernel<F_HID, 4, true, true><<<N_PAD / 4, 256, 0, stream>>>(
        h1, offs, srcx, dinv, b1, h2, nullptr, Nn, N_PAD);

    // layer 2
    gemm_kernel<4, 1, 2, 4><<<dim3(N_PAD / 128, 1), 256, 0, stream>>>(
        h2, w2t, t2, F_HID, F_OUT);
    agg_kernel<F_OUT, 1, false, false><<<(Nn + 3) / 4, 256, 0, stream>>>(
        t2, offs, srcx, dinv, b2, nullptr, (float*)d_out, Nn, Nn);
}

// Round 2
// 470.554 us; speedup vs baseline: 1.2024x; 1.2024x over previous
//
#include <hip/hip_runtime.h>

// ---------------------------------------------------------------------------
// GCN 2-layer forward on MI355X.
//   h1 = X @ W1                  (fused f32->bf16 MFMA GEMM, 50000x512x256)
//   h2 = relu(Ahat @ h1 + b1)    (CSR gather-accumulate, bf16 msgs)
//   t2 = h2 @ W2                 (bf16 MFMA GEMM, 50000x256x64)
//   out = Ahat @ t2 + b2         (CSR gather-accumulate, fp32 out)
// Ahat = D^-1/2 (A + I) D^-1/2 built on device each call (counting sort,
// multi-block scan).
// ---------------------------------------------------------------------------

typedef __bf16 bf16x8 __attribute__((ext_vector_type(8)));
typedef __bf16 bf16x4 __attribute__((ext_vector_type(4)));
typedef float  f32x4  __attribute__((ext_vector_type(4)));

#define N_NODES 50000
#define N_PAD   50048   // 391 * 128
#define F_IN    512
#define F_HID   256
#define F_OUT   64
#define SCAN_B  196     // ceil(50000 / 256)

// ---------------------------------------------------------------------------
// W [K][N] f32 -> WT [N][K] bf16 (transpose so MFMA B-fragments are contiguous k)
__global__ __launch_bounds__(256) void convw_kernel(
    const float* __restrict__ W, __bf16* __restrict__ WT, int K, int N)
{
    int i = blockIdx.x * blockDim.x + threadIdx.x;
    if (i >= N * K) return;
    int n = i / K, k = i - n * K;
    WT[i] = (__bf16)W[(size_t)k * N + n];
}

// ---------------------------------------------------------------------------
// CSR build: histogram, multi-block exclusive scan (+self-loop), sort fill
__global__ __launch_bounds__(256) void count_kernel(
    const int* __restrict__ col, int E, int Nn, int* __restrict__ cnt)
{
    int e = blockIdx.x * blockDim.x + threadIdx.x;
    if (e < E) {
        int c = col[e];
        if ((unsigned)c < (unsigned)Nn) atomicAdd(&cnt[c], 1);
    }
}

// per-block sums of (cnt[i]+1)
__global__ __launch_bounds__(256) void scan_partial_kernel(
    const int* __restrict__ cnt, int* __restrict__ bsum, int N)
{
    __shared__ int s[256];
    const int t = threadIdx.x;
    const int i = blockIdx.x * 256 + t;
    int v = (i < N) ? cnt[i] + 1 : 0;
    s[t] = v;
    __syncthreads();
    #pragma unroll
    for (int off = 128; off > 0; off >>= 1) {
        if (t < off) s[t] += s[t + off];
        __syncthreads();
    }
    if (t == 0) bsum[blockIdx.x] = s[0];
}

// scan the 196 block sums (1 block)
__global__ __launch_bounds__(256) void scan_bsum_kernel(
    const int* __restrict__ bsum, int* __restrict__ bofs,
    int* __restrict__ offs, int N, int PB)
{
    __shared__ int s[256];
    const int t = threadIdx.x;
    int v = (t < PB) ? bsum[t] : 0;
    s[t] = v;
    __syncthreads();
    #pragma unroll
    for (int off = 1; off < 256; off <<= 1) {
        int u = (t >= off) ? s[t - off] : 0;
        __syncthreads();
        s[t] += u;
        __syncthreads();
    }
    if (t < PB) bofs[t] = s[t] - v;      // exclusive
    if (t == 255) offs[N] = s[255];      // grand total (zeros padded beyond PB)
}

// per-block local exclusive scan + bofs -> offs, dinv
__global__ __launch_bounds__(256) void scan_fill_kernel(
    const int* __restrict__ cnt, const int* __restrict__ bofs,
    int* __restrict__ offs, float* __restrict__ dinv, int N)
{
    __shared__ int s[256];
    const int t = threadIdx.x;
    const int i = blockIdx.x * 256 + t;
    int c = (i < N) ? cnt[i] + 1 : 0;
    s[t] = c;
    __syncthreads();
    #pragma unroll
    for (int off = 1; off < 256; off <<= 1) {
        int u = (t >= off) ? s[t - off] : 0;
        __syncthreads();
        s[t] += u;
        __syncthreads();
    }
    if (i < N) {
        offs[i] = bofs[blockIdx.x] + s[t] - c;
        dinv[i] = rsqrtf((float)c);
    }
}

__global__ __launch_bounds__(256) void fill_kernel(
    const int* __restrict__ row, const int* __restrict__ col,
    int E, int Nn, const int* __restrict__ offs,
    int* __restrict__ fill, int* __restrict__ srcidx)
{
    int e = blockIdx.x * blockDim.x + threadIdx.x;
    if (e < E) {
        int c = col[e];
        int r = row[e];
        if ((unsigned)c < (unsigned)Nn && (unsigned)r < (unsigned)Nn) {
            int p = offs[c] + atomicAdd(&fill[c], 1);
            srcidx[p] = r;
        }
    } else {
        int i = e - E;
        if (i < Nn) {
            int p = offs[i] + atomicAdd(&fill[i], 1);
            srcidx[p] = i;   // self loop
        }
    }
}

// ---------------------------------------------------------------------------
// GEMM1 fused: C[50048][256] = cvt_bf16(Xf32)[50048][512] * W1T[256][512]^T
// BM=128, BN=256 (full N, A read once), BK=32, 4 waves (2x2), 16x16x32 MFMA.
__global__ __launch_bounds__(256) void gemm1_kernel(
    const float* __restrict__ A, const __bf16* __restrict__ BT,
    __bf16* __restrict__ C)
{
    constexpr int BK = 32;
    constexpr int LDT = BK + 8;               // 80B row stride in LDS
    __shared__ __bf16 As[128 * LDT];
    __shared__ __bf16 Bs[256 * LDT];

    const int tid  = threadIdx.x;
    const int lane = tid & 63;
    const int wid  = tid >> 6;
    const int wm = wid >> 1, wn = wid & 1;
    const int bm = blockIdx.x * 128;
    const int lr = lane & 15, kg = lane >> 4;

    const int ar  = tid & 127;                // A stage row
    const int as_ = (tid >> 7) * 16;          // A stage k-seg (0 or 16)
    const bool arow_ok = (bm + ar) < N_NODES;
    const float4* ap = (const float4*)(A + (size_t)(bm + ar) * F_IN + as_);
    const bf16x8* bp = (const bf16x8*)(BT + (size_t)tid * F_IN);

    f32x4 acc[4][8] = {};

    for (int k0 = 0; k0 < F_IN; k0 += BK) {
        float4 fa[4];
        if (arow_ok) {
            const float4* p = ap + (k0 >> 2);
            fa[0] = p[0]; fa[1] = p[1]; fa[2] = p[2]; fa[3] = p[3];
        } else {
            #pragma unroll
            for (int j = 0; j < 4; ++j) fa[j] = make_float4(0.f, 0.f, 0.f, 0.f);
        }
        bf16x8 rb[4];
        {
            const bf16x8* q = bp + (k0 >> 3);
            rb[0] = q[0]; rb[1] = q[1]; rb[2] = q[2]; rb[3] = q[3];
        }
        __syncthreads();
        bf16x8 wa0, wa1;
        wa0[0]=(__bf16)fa[0].x; wa0[1]=(__bf16)fa[0].y; wa0[2]=(__bf16)fa[0].z; wa0[3]=(__bf16)fa[0].w;
        wa0[4]=(__bf16)fa[1].x; wa0[5]=(__bf16)fa[1].y; wa0[6]=(__bf16)fa[1].z; wa0[7]=(__bf16)fa[1].w;
        wa1[0]=(__bf16)fa[2].x; wa1[1]=(__bf16)fa[2].y; wa1[2]=(__bf16)fa[2].z; wa1[3]=(__bf16)fa[2].w;
        wa1[4]=(__bf16)fa[3].x; wa1[5]=(__bf16)fa[3].y; wa1[6]=(__bf16)fa[3].z; wa1[7]=(__bf16)fa[3].w;
        *(bf16x8*)(As + ar * LDT + as_)     = wa0;
        *(bf16x8*)(As + ar * LDT + as_ + 8) = wa1;
        #pragma unroll
        for (int j = 0; j < 4; ++j)
            *(bf16x8*)(Bs + tid * LDT + j * 8) = rb[j];
        __syncthreads();

        bf16x8 af[4], bfr[8];
        #pragma unroll
        for (int m = 0; m < 4; ++m)
            af[m] = *(const bf16x8*)(As + (wm * 64 + m * 16 + lr) * LDT + kg * 8);
        #pragma unroll
        for (int n = 0; n < 8; ++n)
            bfr[n] = *(const bf16x8*)(Bs + (wn * 128 + n * 16 + lr) * LDT + kg * 8);
        #pragma unroll
        for (int m = 0; m < 4; ++m)
            #pragma unroll
            for (int n = 0; n < 8; ++n)
                acc[m][n] = __builtin_amdgcn_mfma_f32_16x16x32_bf16(
                    af[m], bfr[n], acc[m][n], 0, 0, 0);
    }

    const int crow0 = bm + wm * 64 + kg * 4;
    const int ccol0 = wn * 128 + lr;
    #pragma unroll
    for (int m = 0; m < 4; ++m)
        #pragma unroll
        for (int n = 0; n < 8; ++n)
            #pragma unroll
            for (int j = 0; j < 4; ++j)
                C[(size_t)(crow0 + m * 16 + j) * F_HID + (ccol0 + n * 16)] =
                    (__bf16)acc[m][n][j];
}

// ---------------------------------------------------------------------------
// bf16 MFMA GEMM (layer 2): C[Mpad][N] = A[Mpad][K] * BT[N][K]^T
template<int WGM, int WGN, int FM, int FN>
__global__ __launch_bounds__(256) void gemm_kernel(
    const __bf16* __restrict__ A, const __bf16* __restrict__ BT,
    __bf16* __restrict__ C, int K, int N)
{
    constexpr int BM = WGM * FM * 16;
    constexpr int BN = WGN * FN * 16;
    constexpr int BK = 32;
    constexpr int LDT = BK + 8;
    __shared__ __bf16 As[BM * LDT];
    __shared__ __bf16 Bs[BN * LDT];

    const int tid  = threadIdx.x;
    const int lane = tid & 63;
    const int wid  = tid >> 6;
    const int wm = wid / WGN, wn = wid % WGN;
    const int bm = blockIdx.x * BM;
    const int bn = blockIdx.y * BN;
    const int lr = lane & 15, kg = lane >> 4;

    const int arow = tid >> 2;
    const int achk = (tid & 3) * 8;

    f32x4 acc[FM][FN] = {};

    for (int k0 = 0; k0 < K; k0 += BK) {
        bf16x8 ra[BM / 64], rb[BN / 64];
        #pragma unroll
        for (int p = 0; p < BM / 64; ++p)
            ra[p] = *(const bf16x8*)(A + (size_t)(bm + p * 64 + arow) * K + k0 + achk);
        #pragma unroll
        for (int p = 0; p < BN / 64; ++p)
            rb[p] = *(const bf16x8*)(BT + (size_t)(bn + p * 64 + arow) * K + k0 + achk);
        __syncthreads();
        #pragma unroll
        for (int p = 0; p < BM / 64; ++p)
            *(bf16x8*)(As + (p * 64 + arow) * LDT + achk) = ra[p];
        #pragma unroll
        for (int p = 0; p < BN / 64; ++p)
            *(bf16x8*)(Bs + (p * 64 + arow) * LDT + achk) = rb[p];
        __syncthreads();

        bf16x8 af[FM], bfv[FN];
        #pragma unroll
        for (int m = 0; m < FM; ++m)
            af[m] = *(const bf16x8*)(As + (wm * FM * 16 + m * 16 + lr) * LDT + kg * 8);
        #pragma unroll
        for (int n = 0; n < FN; ++n)
            bfv[n] = *(const bf16x8*)(Bs + (wn * FN * 16 + n * 16 + lr) * LDT + kg * 8);
        #pragma unroll
        for (int m = 0; m < FM; ++m)
            #pragma unroll
            for (int n = 0; n < FN; ++n)
                acc[m][n] = __builtin_amdgcn_mfma_f32_16x16x32_bf16(
                    af[m], bfv[n], acc[m][n], 0, 0, 0);
    }

    const int crow0 = bm + wm * FM * 16 + kg * 4;
    const int ccol0 = bn + wn * FN * 16 + lr;
    #pragma unroll
    for (int m = 0; m < FM; ++m)
        #pragma unroll
        for (int n = 0; n < FN; ++n)
            #pragma unroll
            for (int j = 0; j < 4; ++j)
                C[(size_t)(crow0 + m * 16 + j) * N + (ccol0 + n * 16)] =
                    (__bf16)acc[m][n][j];
}

// ---------------------------------------------------------------------------
// CSR aggregation: one wave per node. out[n][f] = dinv[n]*sum_e dinv[src]*H[src][f] (+bias)
template<int F, int FP, bool RELU, bool BF16OUT>
__global__ __launch_bounds__(256) void agg_kernel(
    const __bf16* __restrict__ H,
    const int* __restrict__ offs, const int* __restrict__ srcidx,
    const float* __restrict__ dinv, const float* __restrict__ bias,
    __bf16* __restrict__ outb, float* __restrict__ outf,
    int Nn, int Mpad)
{
    const int lane = threadIdx.x & 63;
    const int node = blockIdx.x * 4 + (threadIdx.x >> 6);
    if (node >= Mpad) return;
    if (node >= Nn) {
        if (BF16OUT) {
            #pragma unroll
            for (int j = 0; j < FP; ++j)
                outb[(size_t)node * F + lane * FP + j] = (__bf16)0.f;
        }
        return;
    }
    const int e0 = offs[node], e1 = offs[node + 1];
    const float dv = dinv[node];
    float acc[FP] = {};
    for (int e = e0; e < e1; ++e) {
        int s = srcidx[e];
        float w = dinv[s];
        const __bf16* hp = H + (size_t)s * F + lane * FP;
        if constexpr (FP == 4) {
            bf16x4 v = *(const bf16x4*)hp;
            #pragma unroll
            for (int j = 0; j < 4; ++j) acc[j] += w * (float)v[j];
        } else {
            acc[0] += w * (float)hp[0];
        }
    }
    if constexpr (BF16OUT) {
        bf16x4 ov;
        #pragma unroll
        for (int j = 0; j < FP; ++j) {
            float r = dv * acc[j] + bias[lane * FP + j];
            if (RELU) r = fmaxf(r, 0.f);
            if constexpr (FP == 4) ov[j] = (__bf16)r;
            else outb[(size_t)node * F + lane] = (__bf16)r;
        }
        if constexpr (FP == 4)
            *(bf16x4*)(outb + (size_t)node * F + lane * 4) = ov;
    } else {
        #pragma unroll
        for (int j = 0; j < FP; ++j) {
            float r = dv * acc[j] + bias[lane * FP + j];
            if (RELU) r = fmaxf(r, 0.f);
            outf[(size_t)node * F + lane * FP + j] = r;
        }
    }
}

// ---------------------------------------------------------------------------
extern "C" void kernel_launch(void* const* d_in, const int* in_sizes, int n_in,
                              void* d_out, int out_size, void* d_ws, size_t ws_size,
                              hipStream_t stream)
{
    const float* x   = (const float*)d_in[0];
    const int*   ei  = (const int*)d_in[1];
    const float* W1  = (const float*)d_in[2];
    const float* b1  = (const float*)d_in[3];
    const float* W2  = (const float*)d_in[4];
    const float* b2  = (const float*)d_in[5];
    const int E  = in_sizes[1] / 2;
    const int Nn = N_NODES;
    const int E2 = E + Nn;
    const int* rowp = ei;
    const int* colp = ei + E;

    char* w = (char*)d_ws;
    auto alloc = [&](size_t bytes) {
        char* p = w; w += (bytes + 255) & ~(size_t)255; return p;
    };
    __bf16* h1   = (__bf16*)alloc((size_t)N_PAD * F_HID * 2);  // reused as t2
    __bf16* h2   = (__bf16*)alloc((size_t)N_PAD * F_HID * 2);
    __bf16* w1t  = (__bf16*)alloc((size_t)F_HID * F_IN  * 2);
    __bf16* w2t  = (__bf16*)alloc((size_t)F_OUT * F_HID * 2);
    int*    cnt  = (int*)  alloc((size_t)Nn * 4);
    int*    fil  = (int*)  alloc((size_t)Nn * 4);
    int*    offs = (int*)  alloc((size_t)(Nn + 1) * 4);
    float*  dinv = (float*)alloc((size_t)Nn * 4);
    int*    bsum = (int*)  alloc((size_t)SCAN_B * 4);
    int*    bofs = (int*)  alloc((size_t)SCAN_B * 4);
    int*    srcx = (int*)  alloc((size_t)E2 * 4);
    __bf16* t2 = h1;    // h1 dead after agg1

    hipMemsetAsync(cnt, 0, (size_t)Nn * 4, stream);
    hipMemsetAsync(fil, 0, (size_t)Nn * 4, stream);

    convw_kernel<<<(F_IN * F_HID + 255) / 256, 256, 0, stream>>>(W1, w1t, F_IN, F_HID);
    convw_kernel<<<(F_HID * F_OUT + 255) / 256, 256, 0, stream>>>(W2, w2t, F_HID, F_OUT);

    // CSR build (multi-block scan)
    count_kernel<<<(E + 255) / 256, 256, 0, stream>>>(colp, E, Nn, cnt);
    scan_partial_kernel<<<SCAN_B, 256, 0, stream>>>(cnt, bsum, Nn);
    scan_bsum_kernel<<<1, 256, 0, stream>>>(bsum, bofs, offs, Nn, SCAN_B);
    scan_fill_kernel<<<SCAN_B, 256, 0, stream>>>(cnt, bofs, offs, dinv, Nn);
    fill_kernel<<<(E2 + 255) / 256, 256, 0, stream>>>(rowp, colp, E, Nn, offs, fil, srcx);

    // layer 1 (conversion fused into GEMM1; A read once with BN=256)
    gemm1_kernel<<<N_PAD / 128, 256, 0, stream>>>(x, w1t, h1);
    agg_kernel<F_HID, 4, true, true><<<N_PAD / 4, 256, 0, stream>>>(
        h1, offs, srcx, dinv, b1, h2, nullptr, Nn, N_PAD);

    // layer 2
    gemm_kernel<4, 1, 2, 4><<<dim3(N_PAD / 128, 1), 256, 0, stream>>>(
        h2, w2t, t2, F_HID, F_OUT);
    agg_kernel<F_OUT, 1, false, false><<<(Nn + 3) / 4, 256, 0, stream>>>(
        t2, offs, srcx, dinv, b2, nullptr, (float*)d_out, Nn, Nn);
}

// Round 5
// 393.894 us; speedup vs baseline: 1.4364x; 1.1946x over previous
//
#include <hip/hip_runtime.h>

// ---------------------------------------------------------------------------
// GCN 2-layer forward on MI355X.
//   h1s = dinv * (X @ W1)            (fused f32->bf16 MFMA GEMM + norm epilogue)
//   h2  = relu(dinv * sum h1s + b1)  (CSR gather, 4-deep pipelined, bf16)
//   t2s = dinv * (h2 @ W2)           (bf16 MFMA GEMM + norm epilogue)
//   out = dinv * sum t2s + b2        (CSR gather, fp32 out)
// Ahat = D^-1/2 (A+I) D^-1/2; dinv folded into GEMM epilogues so the edge
// loop has no per-edge weight gather. CSR segments padded to %4 with a
// dummy src pointing at the all-zero pad row (ZERO_ROW) -> tail-free int4
// index loads + 4 independent row loads in flight per wave.
// ---------------------------------------------------------------------------

typedef __bf16 bf16x8 __attribute__((ext_vector_type(8)));
typedef __bf16 bf16x4 __attribute__((ext_vector_type(4)));
typedef float  f32x4  __attribute__((ext_vector_type(4)));

#define N_NODES  50000
#define N_PAD    50048   // 391 * 128
#define ZERO_ROW 50000   // first pad row: always all-zero in h1s/h2/t2s
#define F_IN     512
#define F_HID    256
#define F_OUT    64
#define SCAN_B   196     // ceil(50000 / 256)

// ---------------------------------------------------------------------------
// W [K][N] f32 -> WT [N][K] bf16
__global__ __launch_bounds__(256) void convw_kernel(
    const float* __restrict__ W, __bf16* __restrict__ WT, int K, int N)
{
    int i = blockIdx.x * blockDim.x + threadIdx.x;
    if (i >= N * K) return;
    int n = i / K, k = i - n * K;
    WT[i] = (__bf16)W[(size_t)k * N + n];
}

// srcidx init: every slot points at the zero row (pad slots keep this)
__global__ __launch_bounds__(256) void initsrc_kernel(
    int* __restrict__ srcidx, int n4)
{
    int i = blockIdx.x * blockDim.x + threadIdx.x;
    if (i < n4) {
        int4 v = make_int4(ZERO_ROW, ZERO_ROW, ZERO_ROW, ZERO_ROW);
        *(int4*)(srcidx + i * 4) = v;
    }
}

// ---------------------------------------------------------------------------
// CSR build: histogram, multi-block exclusive scan of padded caps, sort fill
__global__ __launch_bounds__(256) void count_kernel(
    const int* __restrict__ col, int E, int Nn, int* __restrict__ cnt)
{
    int e = blockIdx.x * blockDim.x + threadIdx.x;
    if (e < E) {
        int c = col[e];
        if ((unsigned)c < (unsigned)Nn) atomicAdd(&cnt[c], 1);
    }
}

// per-block sums of padded capacity cap_i = round4(cnt[i]+1)
__global__ __launch_bounds__(256) void scan_partial_kernel(
    const int* __restrict__ cnt, int* __restrict__ bsum, int N)
{
    __shared__ int s[256];
    const int t = threadIdx.x;
    const int i = blockIdx.x * 256 + t;
    int v = (i < N) ? ((cnt[i] + 1 + 3) & ~3) : 0;
    s[t] = v;
    __syncthreads();
    #pragma unroll
    for (int off = 128; off > 0; off >>= 1) {
        if (t < off) s[t] += s[t + off];
        __syncthreads();
    }
    if (t == 0) bsum[blockIdx.x] = s[0];
}

__global__ __launch_bounds__(256) void scan_bsum_kernel(
    const int* __restrict__ bsum, int* __restrict__ bofs,
    int* __restrict__ offs, int N, int PB)
{
    __shared__ int s[256];
    const int t = threadIdx.x;
    int v = (t < PB) ? bsum[t] : 0;
    s[t] = v;
    __syncthreads();
    #pragma unroll
    for (int off = 1; off < 256; off <<= 1) {
        int u = (t >= off) ? s[t - off] : 0;
        __syncthreads();
        s[t] += u;
        __syncthreads();
    }
    if (t < PB) bofs[t] = s[t] - v;
    if (t == 255) offs[N] = s[255];
}

// per-block local exclusive scan of caps + bofs -> offs; dinv from true degree
__global__ __launch_bounds__(256) void scan_fill_kernel(
    const int* __restrict__ cnt, const int* __restrict__ bofs,
    int* __restrict__ offs, float* __restrict__ dinv, int N)
{
    __shared__ int s[256];
    const int t = threadIdx.x;
    const int i = blockIdx.x * 256 + t;
    int c   = (i < N) ? cnt[i] + 1 : 0;
    int cap = (c + 3) & ~3;
    s[t] = cap;
    __syncthreads();
    #pragma unroll
    for (int off = 1; off < 256; off <<= 1) {
        int u = (t >= off) ? s[t - off] : 0;
        __syncthreads();
        s[t] += u;
        __syncthreads();
    }
    if (i < N) {
        offs[i] = bofs[blockIdx.x] + s[t] - cap;
        dinv[i] = rsqrtf((float)c);
    }
}

__global__ __launch_bounds__(256) void fill_kernel(
    const int* __restrict__ row, const int* __restrict__ col,
    int E, int Nn, const int* __restrict__ offs,
    int* __restrict__ fill, int* __restrict__ srcidx)
{
    int e = blockIdx.x * blockDim.x + threadIdx.x;
    if (e < E) {
        int c = col[e];
        int r = row[e];
        if ((unsigned)c < (unsigned)Nn && (unsigned)r < (unsigned)Nn) {
            int p = offs[c] + atomicAdd(&fill[c], 1);
            srcidx[p] = r;
        }
    } else {
        int i = e - E;
        if (i < Nn) {
            int p = offs[i] + atomicAdd(&fill[i], 1);
            srcidx[p] = i;   // self loop
        }
    }
}

// ---------------------------------------------------------------------------
// GEMM1 fused: C[50048][256] = dinv[r] * (cvt_bf16(Xf32)[50048][512] @ W1T^T)
// BM=128, BN=256 (full N, A read once), BK=32, 4 waves (2x2), 16x16x32 MFMA.
__global__ __launch_bounds__(256) void gemm1_kernel(
    const float* __restrict__ A, const __bf16* __restrict__ BT,
    const float* __restrict__ dinv, __bf16* __restrict__ C)
{
    constexpr int BK = 32;
    constexpr int LDT = BK + 8;
    __shared__ __bf16 As[128 * LDT];
    __shared__ __bf16 Bs[256 * LDT];

    const int tid  = threadIdx.x;
    const int lane = tid & 63;
    const int wid  = tid >> 6;
    const int wm = wid >> 1, wn = wid & 1;
    const int bm = blockIdx.x * 128;
    const int lr = lane & 15, kg = lane >> 4;

    const int ar  = tid & 127;
    const int as_ = (tid >> 7) * 16;
    const bool arow_ok = (bm + ar) < N_NODES;
    const float4* ap = (const float4*)(A + (size_t)(bm + ar) * F_IN + as_);
    const bf16x8* bp = (const bf16x8*)(BT + (size_t)tid * F_IN);

    f32x4 acc[4][8] = {};

    for (int k0 = 0; k0 < F_IN; k0 += BK) {
        float4 fa[4];
        if (arow_ok) {
            const float4* p = ap + (k0 >> 2);
            fa[0] = p[0]; fa[1] = p[1]; fa[2] = p[2]; fa[3] = p[3];
        } else {
            #pragma unroll
            for (int j = 0; j < 4; ++j) fa[j] = make_float4(0.f, 0.f, 0.f, 0.f);
        }
        bf16x8 rb[4];
        {
            const bf16x8* q = bp + (k0 >> 3);
            rb[0] = q[0]; rb[1] = q[1]; rb[2] = q[2]; rb[3] = q[3];
        }
        __syncthreads();
        bf16x8 wa0, wa1;
        wa0[0]=(__bf16)fa[0].x; wa0[1]=(__bf16)fa[0].y; wa0[2]=(__bf16)fa[0].z; wa0[3]=(__bf16)fa[0].w;
        wa0[4]=(__bf16)fa[1].x; wa0[5]=(__bf16)fa[1].y; wa0[6]=(__bf16)fa[1].z; wa0[7]=(__bf16)fa[1].w;
        wa1[0]=(__bf16)fa[2].x; wa1[1]=(__bf16)fa[2].y; wa1[2]=(__bf16)fa[2].z; wa1[3]=(__bf16)fa[2].w;
        wa1[4]=(__bf16)fa[3].x; wa1[5]=(__bf16)fa[3].y; wa1[6]=(__bf16)fa[3].z; wa1[7]=(__bf16)fa[3].w;
        *(bf16x8*)(As + ar * LDT + as_)     = wa0;
        *(bf16x8*)(As + ar * LDT + as_ + 8) = wa1;
        #pragma unroll
        for (int j = 0; j < 4; ++j)
            *(bf16x8*)(Bs + tid * LDT + j * 8) = rb[j];
        __syncthreads();

        bf16x8 af[4], bfr[8];
        #pragma unroll
        for (int m = 0; m < 4; ++m)
            af[m] = *(const bf16x8*)(As + (wm * 64 + m * 16 + lr) * LDT + kg * 8);
        #pragma unroll
        for (int n = 0; n < 8; ++n)
            bfr[n] = *(const bf16x8*)(Bs + (wn * 128 + n * 16 + lr) * LDT + kg * 8);
        #pragma unroll
        for (int m = 0; m < 4; ++m)
            #pragma unroll
            for (int n = 0; n < 8; ++n)
                acc[m][n] = __builtin_amdgcn_mfma_f32_16x16x32_bf16(
                    af[m], bfr[n], acc[m][n], 0, 0, 0);
    }

    const int crow0 = bm + wm * 64 + kg * 4;
    const int ccol0 = wn * 128 + lr;
    #pragma unroll
    for (int m = 0; m < 4; ++m) {
        #pragma unroll
        for (int j = 0; j < 4; ++j) {
            int r = crow0 + m * 16 + j;
            float dv = (r < N_NODES) ? dinv[r] : 0.f;
            #pragma unroll
            for (int n = 0; n < 8; ++n)
                C[(size_t)r * F_HID + (ccol0 + n * 16)] = (__bf16)(dv * acc[m][n][j]);
        }
    }
}

// ---------------------------------------------------------------------------
// GEMM2: C[Mpad][N] = dinv[r] * (A[Mpad][K] @ BT[N][K]^T)
template<int WGM, int WGN, int FM, int FN>
__global__ __launch_bounds__(256) void gemm_kernel(
    const __bf16* __restrict__ A, const __bf16* __restrict__ BT,
    const float* __restrict__ dinv, __bf16* __restrict__ C, int K, int N)
{
    constexpr int BM = WGM * FM * 16;
    constexpr int BN = WGN * FN * 16;
    constexpr int BK = 32;
    constexpr int LDT = BK + 8;
    __shared__ __bf16 As[BM * LDT];
    __shared__ __bf16 Bs[BN * LDT];

    const int tid  = threadIdx.x;
    const int lane = tid & 63;
    const int wid  = tid >> 6;
    const int wm = wid / WGN, wn = wid % WGN;
    const int bm = blockIdx.x * BM;
    const int bn = blockIdx.y * BN;
    const int lr = lane & 15, kg = lane >> 4;

    const int arow = tid >> 2;
    const int achk = (tid & 3) * 8;

    f32x4 acc[FM][FN] = {};

    for (int k0 = 0; k0 < K; k0 += BK) {
        bf16x8 ra[BM / 64], rb[BN / 64];
        #pragma unroll
        for (int p = 0; p < BM / 64; ++p)
            ra[p] = *(const bf16x8*)(A + (size_t)(bm + p * 64 + arow) * K + k0 + achk);
        #pragma unroll
        for (int p = 0; p < BN / 64; ++p)
            rb[p] = *(const bf16x8*)(BT + (size_t)(bn + p * 64 + arow) * K + k0 + achk);
        __syncthreads();
        #pragma unroll
        for (int p = 0; p < BM / 64; ++p)
            *(bf16x8*)(As + (p * 64 + arow) * LDT + achk) = ra[p];
        #pragma unroll
        for (int p = 0; p < BN / 64; ++p)
            *(bf16x8*)(Bs + (p * 64 + arow) * LDT + achk) = rb[p];
        __syncthreads();

        bf16x8 af[FM], bfv[FN];
        #pragma unroll
        for (int m = 0; m < FM; ++m)
            af[m] = *(const bf16x8*)(As + (wm * FM * 16 + m * 16 + lr) * LDT + kg * 8);
        #pragma unroll
        for (int n = 0; n < FN; ++n)
            bfv[n] = *(const bf16x8*)(Bs + (wn * FN * 16 + n * 16 + lr) * LDT + kg * 8);
        #pragma unroll
        for (int m = 0; m < FM; ++m)
            #pragma unroll
            for (int n = 0; n < FN; ++n)
                acc[m][n] = __builtin_amdgcn_mfma_f32_16x16x32_bf16(
                    af[m], bfv[n], acc[m][n], 0, 0, 0);
    }

    const int crow0 = bm + wm * FM * 16 + kg * 4;
    const int ccol0 = bn + wn * FN * 16 + lr;
    #pragma unroll
    for (int m = 0; m < FM; ++m) {
        #pragma unroll
        for (int j = 0; j < 4; ++j) {
            int r = crow0 + m * 16 + j;
            float dv = (r < N_NODES) ? dinv[r] : 0.f;
            #pragma unroll
            for (int n = 0; n < FN; ++n)
                C[(size_t)r * N + (ccol0 + n * 16)] = (__bf16)(dv * acc[m][n][j]);
        }
    }
}

// ---------------------------------------------------------------------------
// CSR aggregation, 4-deep: out[n][f] = dinv[n]*sum_e Hs[src[e]][f] + bias[f]
// Segments are padded to %4 with ZERO_ROW (all-zero row) -> no tail, int4
// index loads, 4 independent row loads in flight.
template<int F, int FP, bool RELU, bool BF16OUT>
__global__ __launch_bounds__(256) void agg_kernel(
    const __bf16* __restrict__ H,
    const int* __restrict__ offs, const int* __restrict__ srcidx,
    const float* __restrict__ dinv, const float* __restrict__ bias,
    __bf16* __restrict__ outb, float* __restrict__ outf,
    int Nn, int Mpad)
{
    const int lane = threadIdx.x & 63;
    const int node = blockIdx.x * 4 + (threadIdx.x >> 6);
    if (node >= Mpad) return;
    if (node >= Nn) {
        if (BF16OUT) {
            #pragma unroll
            for (int j = 0; j < FP; ++j)
                outb[(size_t)node * F + lane * FP + j] = (__bf16)0.f;
        }
        return;
    }
    const int e0 = offs[node], e1 = offs[node + 1];   // both %4 == 0
    const float dv = dinv[node];
    float acc[FP] = {};
    for (int e = e0; e < e1; e += 4) {
        int4 ss = *(const int4*)(srcidx + e);
        if constexpr (FP == 4) {
            bf16x4 v0 = *(const bf16x4*)(H + (size_t)ss.x * F + lane * 4);
            bf16x4 v1 = *(const bf16x4*)(H + (size_t)ss.y * F + lane * 4);
            bf16x4 v2 = *(const bf16x4*)(H + (size_t)ss.z * F + lane * 4);
            bf16x4 v3 = *(const bf16x4*)(H + (size_t)ss.w * F + lane * 4);
            #pragma unroll
            for (int j = 0; j < 4; ++j)
                acc[j] += (float)v0[j] + (float)v1[j] + (float)v2[j] + (float)v3[j];
        } else {
            __bf16 v0 = H[(size_t)ss.x * F + lane];
            __bf16 v1 = H[(size_t)ss.y * F + lane];
            __bf16 v2 = H[(size_t)ss.z * F + lane];
            __bf16 v3 = H[(size_t)ss.w * F + lane];
            acc[0] += (float)v0 + (float)v1 + (float)v2 + (float)v3;
        }
    }
    if constexpr (BF16OUT) {
        bf16x4 ov;
        #pragma unroll
        for (int j = 0; j < FP; ++j) {
            float r = dv * acc[j] + bias[lane * FP + j];
            if (RELU) r = fmaxf(r, 0.f);
            if constexpr (FP == 4) ov[j] = (__bf16)r;
            else outb[(size_t)node * F + lane] = (__bf16)r;
        }
        if constexpr (FP == 4)
            *(bf16x4*)(outb + (size_t)node * F + lane * 4) = ov;
    } else {
        #pragma unroll
        for (int j = 0; j < FP; ++j) {
            float r = dv * acc[j] + bias[lane * FP + j];
            if (RELU) r = fmaxf(r, 0.f);
            outf[(size_t)node * F + lane * FP + j] = r;
        }
    }
}

// ---------------------------------------------------------------------------
extern "C" void kernel_launch(void* const* d_in, const int* in_sizes, int n_in,
                              void* d_out, int out_size, void* d_ws, size_t ws_size,
                              hipStream_t stream)
{
    const float* x   = (const float*)d_in[0];
    const int*   ei  = (const int*)d_in[1];
    const float* W1  = (const float*)d_in[2];
    const float* b1  = (const float*)d_in[3];
    const float* W2  = (const float*)d_in[4];
    const float* b2  = (const float*)d_in[5];
    const int E  = in_sizes[1] / 2;
    const int Nn = N_NODES;
    const int E2 = E + Nn;
    const int E2P = E + 4 * Nn;            // padded-CSR capacity upper bound
    const int* rowp = ei;
    const int* colp = ei + E;

    char* w = (char*)d_ws;
    auto alloc = [&](size_t bytes) {
        char* p = w; w += (bytes + 255) & ~(size_t)255; return p;
    };
    __bf16* h1   = (__bf16*)alloc((size_t)N_PAD * F_HID * 2);  // reused as t2
    __bf16* h2   = (__bf16*)alloc((size_t)N_PAD * F_HID * 2);
    __bf16* w1t  = (__bf16*)alloc((size_t)F_HID * F_IN  * 2);
    __bf16* w2t  = (__bf16*)alloc((size_t)F_OUT * F_HID * 2);
    int*    cnt  = (int*)  alloc((size_t)Nn * 4);
    int*    fil  = (int*)  alloc((size_t)Nn * 4);
    int*    offs = (int*)  alloc((size_t)(Nn + 1) * 4);
    float*  dinv = (float*)alloc((size_t)Nn * 4);
    int*    bsum = (int*)  alloc((size_t)SCAN_B * 4);
    int*    bofs = (int*)  alloc((size_t)SCAN_B * 4);
    int*    srcx = (int*)  alloc((size_t)E2P * 4);
    __bf16* t2 = h1;    // h1 dead after agg1

    hipMemsetAsync(cnt, 0, (size_t)Nn * 4, stream);
    hipMemsetAsync(fil, 0, (size_t)Nn * 4, stream);
    initsrc_kernel<<<(E2P / 4 + 255) / 256, 256, 0, stream>>>(srcx, E2P / 4);

    convw_kernel<<<(F_IN * F_HID + 255) / 256, 256, 0, stream>>>(W1, w1t, F_IN, F_HID);
    convw_kernel<<<(F_HID * F_OUT + 255) / 256, 256, 0, stream>>>(W2, w2t, F_HID, F_OUT);

    // CSR build (multi-block scan over padded caps)
    count_kernel<<<(E + 255) / 256, 256, 0, stream>>>(colp, E, Nn, cnt);
    scan_partial_kernel<<<SCAN_B, 256, 0, stream>>>(cnt, bsum, Nn);
    scan_bsum_kernel<<<1, 256, 0, stream>>>(bsum, bofs, offs, Nn, SCAN_B);
    scan_fill_kernel<<<SCAN_B, 256, 0, stream>>>(cnt, bofs, offs, dinv, Nn);
    fill_kernel<<<(E2 + 255) / 256, 256, 0, stream>>>(rowp, colp, E, Nn, offs, fil, srcx);

    // layer 1
    gemm1_kernel<<<N_PAD / 128, 256, 0, stream>>>(x, w1t, dinv, h1);
    agg_kernel<F_HID, 4, true, true><<<N_PAD / 4, 256, 0, stream>>>(
        h1, offs, srcx, dinv, b1, h2, nullptr, Nn, N_PAD);

    // layer 2
    gemm_kernel<4, 1, 2, 4><<<dim3(N_PAD / 128, 1), 256, 0, stream>>>(
        h2, w2t, dinv, t2, F_HID, F_OUT);
    agg_kernel<F_OUT, 1, false, false><<<(Nn + 3) / 4, 256, 0, stream>>>(
        t2, offs, srcx, dinv, b2, nullptr, (float*)d_out, Nn, Nn);
}

// Round 8
// 390.116 us; speedup vs baseline: 1.4503x; 1.0097x over previous
//
#include <hip/hip_runtime.h>

// ---------------------------------------------------------------------------
// GCN 2-layer forward on MI355X.
//   h1s = dinv * (X @ W1)            (fused f32->bf16 MFMA GEMM + norm epilogue)
//   h2  = relu(dinv * sum h1s + b1)  (CSR gather, 4-deep pipelined, bf16)
//   t2s = dinv * (h2 @ W2)           (bf16 MFMA GEMM + norm epilogue)
//   out = dinv * sum t2s + b2        (CSR gather, fp32 out)
// R6: GEMM tiles BM 128->64 (grid 391->782 blocks, ~3 blocks/CU) to fix the
// 8.5%-occupancy latency stall seen in rocprof (1.5 waves/SIMD before).
// ---------------------------------------------------------------------------

typedef __bf16 bf16x8 __attribute__((ext_vector_type(8)));
typedef __bf16 bf16x4 __attribute__((ext_vector_type(4)));
typedef float  f32x4  __attribute__((ext_vector_type(4)));

#define N_NODES  50000
#define N_PAD    50048   // 391 * 128 (rows padded; GEMM block rows = 64 -> 782)
#define ZERO_ROW 50000   // first pad row: always all-zero in h1s/h2/t2s
#define F_IN     512
#define F_HID    256
#define F_OUT    64
#define SCAN_B   196     // ceil(50000 / 256)

// ---------------------------------------------------------------------------
// W [K][N] f32 -> WT [N][K] bf16
__global__ __launch_bounds__(256) void convw_kernel(
    const float* __restrict__ W, __bf16* __restrict__ WT, int K, int N)
{
    int i = blockIdx.x * blockDim.x + threadIdx.x;
    if (i >= N * K) return;
    int n = i / K, k = i - n * K;
    WT[i] = (__bf16)W[(size_t)k * N + n];
}

// srcidx init: every slot points at the zero row (pad slots keep this)
__global__ __launch_bounds__(256) void initsrc_kernel(
    int* __restrict__ srcidx, int n4)
{
    int i = blockIdx.x * blockDim.x + threadIdx.x;
    if (i < n4) {
        int4 v = make_int4(ZERO_ROW, ZERO_ROW, ZERO_ROW, ZERO_ROW);
        *(int4*)(srcidx + i * 4) = v;
    }
}

// ---------------------------------------------------------------------------
// CSR build: histogram, multi-block exclusive scan of padded caps, sort fill
__global__ __launch_bounds__(256) void count_kernel(
    const int* __restrict__ col, int E, int Nn, int* __restrict__ cnt)
{
    int e = blockIdx.x * blockDim.x + threadIdx.x;
    if (e < E) {
        int c = col[e];
        if ((unsigned)c < (unsigned)Nn) atomicAdd(&cnt[c], 1);
    }
}

// per-block sums of padded capacity cap_i = round4(cnt[i]+1)
__global__ __launch_bounds__(256) void scan_partial_kernel(
    const int* __restrict__ cnt, int* __restrict__ bsum, int N)
{
    __shared__ int s[256];
    const int t = threadIdx.x;
    const int i = blockIdx.x * 256 + t;
    int v = (i < N) ? ((cnt[i] + 1 + 3) & ~3) : 0;
    s[t] = v;
    __syncthreads();
    #pragma unroll
    for (int off = 128; off > 0; off >>= 1) {
        if (t < off) s[t] += s[t + off];
        __syncthreads();
    }
    if (t == 0) bsum[blockIdx.x] = s[0];
}

__global__ __launch_bounds__(256) void scan_bsum_kernel(
    const int* __restrict__ bsum, int* __restrict__ bofs,
    int* __restrict__ offs, int N, int PB)
{
    __shared__ int s[256];
    const int t = threadIdx.x;
    int v = (t < PB) ? bsum[t] : 0;
    s[t] = v;
    __syncthreads();
    #pragma unroll
    for (int off = 1; off < 256; off <<= 1) {
        int u = (t >= off) ? s[t - off] : 0;
        __syncthreads();
        s[t] += u;
        __syncthreads();
    }
    if (t < PB) bofs[t] = s[t] - v;
    if (t == 255) offs[N] = s[255];
}

// per-block local exclusive scan of caps + bofs -> offs; dinv from true degree
__global__ __launch_bounds__(256) void scan_fill_kernel(
    const int* __restrict__ cnt, const int* __restrict__ bofs,
    int* __restrict__ offs, float* __restrict__ dinv, int N)
{
    __shared__ int s[256];
    const int t = threadIdx.x;
    const int i = blockIdx.x * 256 + t;
    int c   = (i < N) ? cnt[i] + 1 : 0;
    int cap = (c + 3) & ~3;
    s[t] = cap;
    __syncthreads();
    #pragma unroll
    for (int off = 1; off < 256; off <<= 1) {
        int u = (t >= off) ? s[t - off] : 0;
        __syncthreads();
        s[t] += u;
        __syncthreads();
    }
    if (i < N) {
        offs[i] = bofs[blockIdx.x] + s[t] - cap;
        dinv[i] = rsqrtf((float)c);
    }
}

__global__ __launch_bounds__(256) void fill_kernel(
    const int* __restrict__ row, const int* __restrict__ col,
    int E, int Nn, const int* __restrict__ offs,
    int* __restrict__ fill, int* __restrict__ srcidx)
{
    int e = blockIdx.x * blockDim.x + threadIdx.x;
    if (e < E) {
        int c = col[e];
        int r = row[e];
        if ((unsigned)c < (unsigned)Nn && (unsigned)r < (unsigned)Nn) {
            int p = offs[c] + atomicAdd(&fill[c], 1);
            srcidx[p] = r;
        }
    } else {
        int i = e - E;
        if (i < Nn) {
            int p = offs[i] + atomicAdd(&fill[i], 1);
            srcidx[p] = i;   // self loop
        }
    }
}

// ---------------------------------------------------------------------------
// GEMM1 fused: C[50048][256] = dinv[r] * (cvt_bf16(Xf32)[50048][512] @ W1T^T)
// BM=64, BN=256 (full N, A read once), BK=32, 4 waves (2x2 -> 32x128 each),
// 782 blocks (~3/CU) for latency hiding. 16x16x32 MFMA.
__global__ __launch_bounds__(256) void gemm1_kernel(
    const float* __restrict__ A, const __bf16* __restrict__ BT,
    const float* __restrict__ dinv, __bf16* __restrict__ C)
{
    constexpr int BK = 32;
    constexpr int LDT = BK + 8;
    __shared__ __bf16 As[64 * LDT];
    __shared__ __bf16 Bs[256 * LDT];

    const int tid  = threadIdx.x;
    const int lane = tid & 63;
    const int wid  = tid >> 6;
    const int wm = wid >> 1, wn = wid & 1;     // 2x2 waves
    const int bm = blockIdx.x * 64;
    const int lr = lane & 15, kg = lane >> 4;

    const int ar   = tid >> 2;                 // 0..63 A stage row
    const int achk = (tid & 3) * 8;            // k-offset of 8-float chunk
    const bool arow_ok = (bm + ar) < N_NODES;
    const float4* ap = (const float4*)(A + (size_t)(bm + ar) * F_IN + achk);
    const bf16x8* bp = (const bf16x8*)(BT + (size_t)tid * F_IN);

    f32x4 acc[2][8] = {};

    for (int k0 = 0; k0 < F_IN; k0 += BK) {
        float4 fa[2];
        if (arow_ok) {
            const float4* p = ap + (k0 >> 2);
            fa[0] = p[0]; fa[1] = p[1];
        } else {
            fa[0] = make_float4(0.f, 0.f, 0.f, 0.f);
            fa[1] = fa[0];
        }
        bf16x8 rb[4];
        {
            const bf16x8* q = bp + (k0 >> 3);
            rb[0] = q[0]; rb[1] = q[1]; rb[2] = q[2]; rb[3] = q[3];
        }
        __syncthreads();
        bf16x8 wa;
        wa[0]=(__bf16)fa[0].x; wa[1]=(__bf16)fa[0].y; wa[2]=(__bf16)fa[0].z; wa[3]=(__bf16)fa[0].w;
        wa[4]=(__bf16)fa[1].x; wa[5]=(__bf16)fa[1].y; wa[6]=(__bf16)fa[1].z; wa[7]=(__bf16)fa[1].w;
        *(bf16x8*)(As + ar * LDT + achk) = wa;
        #pragma unroll
        for (int j = 0; j < 4; ++j)
            *(bf16x8*)(Bs + tid * LDT + j * 8) = rb[j];
        __syncthreads();

        bf16x8 af[2], bfr[8];
        #pragma unroll
        for (int m = 0; m < 2; ++m)
            af[m] = *(const bf16x8*)(As + (wm * 32 + m * 16 + lr) * LDT + kg * 8);
        #pragma unroll
        for (int n = 0; n < 8; ++n)
            bfr[n] = *(const bf16x8*)(Bs + (wn * 128 + n * 16 + lr) * LDT + kg * 8);
        #pragma unroll
        for (int m = 0; m < 2; ++m)
            #pragma unroll
            for (int n = 0; n < 8; ++n)
                acc[m][n] = __builtin_amdgcn_mfma_f32_16x16x32_bf16(
                    af[m], bfr[n], acc[m][n], 0, 0, 0);
    }

    const int crow0 = bm + wm * 32 + kg * 4;
    const int ccol0 = wn * 128 + lr;
    #pragma unroll
    for (int m = 0; m < 2; ++m) {
        #pragma unroll
        for (int j = 0; j < 4; ++j) {
            int r = crow0 + m * 16 + j;
            float dv = (r < N_NODES) ? dinv[r] : 0.f;
            #pragma unroll
            for (int n = 0; n < 8; ++n)
                C[(size_t)r * F_HID + (ccol0 + n * 16)] = (__bf16)(dv * acc[m][n][j]);
        }
    }
}

// ---------------------------------------------------------------------------
// GEMM2: C[Mpad][N] = dinv[r] * (A[Mpad][K] @ BT[N][K]^T)
template<int WGM, int WGN, int FM, int FN>
__global__ __launch_bounds__(256) void gemm_kernel(
    const __bf16* __restrict__ A, const __bf16* __restrict__ BT,
    const float* __restrict__ dinv, __bf16* __restrict__ C, int K, int N)
{
    constexpr int BM = WGM * FM * 16;
    constexpr int BN = WGN * FN * 16;
    constexpr int BK = 32;
    constexpr int LDT = BK + 8;
    __shared__ __bf16 As[BM * LDT];
    __shared__ __bf16 Bs[BN * LDT];

    const int tid  = threadIdx.x;
    const int lane = tid & 63;
    const int wid  = tid >> 6;
    const int wm = wid / WGN, wn = wid % WGN;
    const int bm = blockIdx.x * BM;
    const int bn = blockIdx.y * BN;
    const int lr = lane & 15, kg = lane >> 4;

    const int arow = tid >> 2;
    const int achk = (tid & 3) * 8;

    f32x4 acc[FM][FN] = {};

    for (int k0 = 0; k0 < K; k0 += BK) {
        bf16x8 ra[BM / 64], rb[BN / 64];
        #pragma unroll
        for (int p = 0; p < BM / 64; ++p)
            ra[p] = *(const bf16x8*)(A + (size_t)(bm + p * 64 + arow) * K + k0 + achk);
        #pragma unroll
        for (int p = 0; p < BN / 64; ++p)
            rb[p] = *(const bf16x8*)(BT + (size_t)(bn + p * 64 + arow) * K + k0 + achk);
        __syncthreads();
        #pragma unroll
        for (int p = 0; p < BM / 64; ++p)
            *(bf16x8*)(As + (p * 64 + arow) * LDT + achk) = ra[p];
        #pragma unroll
        for (int p = 0; p < BN / 64; ++p)
            *(bf16x8*)(Bs + (p * 64 + arow) * LDT + achk) = rb[p];
        __syncthreads();

        bf16x8 af[FM], bfv[FN];
        #pragma unroll
        for (int m = 0; m < FM; ++m)
            af[m] = *(const bf16x8*)(As + (wm * FM * 16 + m * 16 + lr) * LDT + kg * 8);
        #pragma unroll
        for (int n = 0; n < FN; ++n)
            bfv[n] = *(const bf16x8*)(Bs + (wn * FN * 16 + n * 16 + lr) * LDT + kg * 8);
        #pragma unroll
        for (int m = 0; m < FM; ++m)
            #pragma unroll
            for (int n = 0; n < FN; ++n)
                acc[m][n] = __builtin_amdgcn_mfma_f32_16x16x32_bf16(
                    af[m], bfv[n], acc[m][n], 0, 0, 0);
    }

    const int crow0 = bm + wm * FM * 16 + kg * 4;
    const int ccol0 = bn + wn * FN * 16 + lr;
    #pragma unroll
    for (int m = 0; m < FM; ++m) {
        #pragma unroll
        for (int j = 0; j < 4; ++j) {
            int r = crow0 + m * 16 + j;
            float dv = (r < N_NODES) ? dinv[r] : 0.f;
            #pragma unroll
            for (int n = 0; n < FN; ++n)
                C[(size_t)r * N + (ccol0 + n * 16)] = (__bf16)(dv * acc[m][n][j]);
        }
    }
}

// ---------------------------------------------------------------------------
// CSR aggregation, 4-deep: out[n][f] = dinv[n]*sum_e Hs[src[e]][f] + bias[f]
template<int F, int FP, bool RELU, bool BF16OUT>
__global__ __launch_bounds__(256) void agg_kernel(
    const __bf16* __restrict__ H,
    const int* __restrict__ offs, const int* __restrict__ srcidx,
    const float* __restrict__ dinv, const float* __restrict__ bias,
    __bf16* __restrict__ outb, float* __restrict__ outf,
    int Nn, int Mpad)
{
    const int lane = threadIdx.x & 63;
    const int node = blockIdx.x * 4 + (threadIdx.x >> 6);
    if (node >= Mpad) return;
    if (node >= Nn) {
        if (BF16OUT) {
            #pragma unroll
            for (int j = 0; j < FP; ++j)
                outb[(size_t)node * F + lane * FP + j] = (__bf16)0.f;
        }
        return;
    }
    const int e0 = offs[node], e1 = offs[node + 1];   // both %4 == 0
    const float dv = dinv[node];
    float acc[FP] = {};
    for (int e = e0; e < e1; e += 4) {
        int4 ss = *(const int4*)(srcidx + e);
        if constexpr (FP == 4) {
            bf16x4 v0 = *(const bf16x4*)(H + (size_t)ss.x * F + lane * 4);
            bf16x4 v1 = *(const bf16x4*)(H + (size_t)ss.y * F + lane * 4);
            bf16x4 v2 = *(const bf16x4*)(H + (size_t)ss.z * F + lane * 4);
            bf16x4 v3 = *(const bf16x4*)(H + (size_t)ss.w * F + lane * 4);
            #pragma unroll
            for (int j = 0; j < 4; ++j)
                acc[j] += (float)v0[j] + (float)v1[j] + (float)v2[j] + (float)v3[j];
        } else {
            __bf16 v0 = H[(size_t)ss.x * F + lane];
            __bf16 v1 = H[(size_t)ss.y * F + lane];
            __bf16 v2 = H[(size_t)ss.z * F + lane];
            __bf16 v3 = H[(size_t)ss.w * F + lane];
            acc[0] += (float)v0 + (float)v1 + (float)v2 + (float)v3;
        }
    }
    if constexpr (BF16OUT) {
        bf16x4 ov;
        #pragma unroll
        for (int j = 0; j < FP; ++j) {
            float r = dv * acc[j] + bias[lane * FP + j];
            if (RELU) r = fmaxf(r, 0.f);
            if constexpr (FP == 4) ov[j] = (__bf16)r;
            else outb[(size_t)node * F + lane] = (__bf16)r;
        }
        if constexpr (FP == 4)
            *(bf16x4*)(outb + (size_t)node * F + lane * 4) = ov;
    } else {
        #pragma unroll
        for (int j = 0; j < FP; ++j) {
            float r = dv * acc[j] + bias[lane * FP + j];
            if (RELU) r = fmaxf(r, 0.f);
            outf[(size_t)node * F + lane * FP + j] = r;
        }
    }
}

// ---------------------------------------------------------------------------
extern "C" void kernel_launch(void* const* d_in, const int* in_sizes, int n_in,
                              void* d_out, int out_size, void* d_ws, size_t ws_size,
                              hipStream_t stream)
{
    const float* x   = (const float*)d_in[0];
    const int*   ei  = (const int*)d_in[1];
    const float* W1  = (const float*)d_in[2];
    const float* b1  = (const float*)d_in[3];
    const float* W2  = (const float*)d_in[4];
    const float* b2  = (const float*)d_in[5];
    const int E  = in_sizes[1] / 2;
    const int Nn = N_NODES;
    const int E2 = E + Nn;
    const int E2P = E + 4 * Nn;            // padded-CSR capacity upper bound
    const int* rowp = ei;
    const int* colp = ei + E;

    char* w = (char*)d_ws;
    auto alloc = [&](size_t bytes) {
        char* p = w; w += (bytes + 255) & ~(size_t)255; return p;
    };
    __bf16* h1   = (__bf16*)alloc((size_t)N_PAD * F_HID * 2);  // reused as t2
    __bf16* h2   = (__bf16*)alloc((size_t)N_PAD * F_HID * 2);
    __bf16* w1t  = (__bf16*)alloc((size_t)F_HID * F_IN  * 2);
    __bf16* w2t  = (__bf16*)alloc((size_t)F_OUT * F_HID * 2);
    int*    cnt  = (int*)  alloc((size_t)Nn * 4);
    int*    fil  = (int*)  alloc((size_t)Nn * 4);
    int*    offs = (int*)  alloc((size_t)(Nn + 1) * 4);
    float*  dinv = (float*)alloc((size_t)Nn * 4);
    int*    bsum = (int*)  alloc((size_t)SCAN_B * 4);
    int*    bofs = (int*)  alloc((size_t)SCAN_B * 4);
    int*    srcx = (int*)  alloc((size_t)E2P * 4);
    __bf16* t2 = h1;    // h1 dead after agg1

    hipMemsetAsync(cnt, 0, (size_t)Nn * 4, stream);
    hipMemsetAsync(fil, 0, (size_t)Nn * 4, stream);
    initsrc_kernel<<<(E2P / 4 + 255) / 256, 256, 0, stream>>>(srcx, E2P / 4);

    convw_kernel<<<(F_IN * F_HID + 255) / 256, 256, 0, stream>>>(W1, w1t, F_IN, F_HID);
    convw_kernel<<<(F_HID * F_OUT + 255) / 256, 256, 0, stream>>>(W2, w2t, F_HID, F_OUT);

    // CSR build (multi-block scan over padded caps)
    count_kernel<<<(E + 255) / 256, 256, 0, stream>>>(colp, E, Nn, cnt);
    scan_partial_kernel<<<SCAN_B, 256, 0, stream>>>(cnt, bsum, Nn);
    scan_bsum_kernel<<<1, 256, 0, stream>>>(bsum, bofs, offs, Nn, SCAN_B);
    scan_fill_kernel<<<SCAN_B, 256, 0, stream>>>(cnt, bofs, offs, dinv, Nn);
    fill_kernel<<<(E2 + 255) / 256, 256, 0, stream>>>(rowp, colp, E, Nn, offs, fil, srcx);

    // layer 1 (BM=64 -> 782 blocks)
    gemm1_kernel<<<N_PAD / 64, 256, 0, stream>>>(x, w1t, dinv, h1);
    agg_kernel<F_HID, 4, true, true><<<N_PAD / 4, 256, 0, stream>>>(
        h1, offs, srcx, dinv, b1, h2, nullptr, Nn, N_PAD);

    // layer 2 (BM=64 -> 782 blocks)
    gemm_kernel<4, 1, 1, 4><<<dim3(N_PAD / 64, 1), 256, 0, stream>>>(
        h2, w2t, dinv, t2, F_HID, F_OUT);
    agg_kernel<F_OUT, 1, false, false><<<(Nn + 3) / 4, 256, 0, stream>>>(
        t2, offs, srcx, dinv, b2, nullptr, (float*)d_out, Nn, Nn);
}